// Round 13
// baseline (38.780 us; speedup 1.0000x reference)
//
#include <hip/hip_runtime.h>
#include <math.h>

#define NB 4096
#define ND 512
#define BM 128
#define BN 256
#define NSPLIT 16   /* NB / BN */
#define KNB 5
#define BKB 64           /* bytes (i8 elems) per row per chunk */
#define CHUNKS (ND / BKB) /* 8 */
#define LDSBUF 24576     /* A:128x64B (8KB) + B:256x64B (16KB) i8 */
#define UMAXV 0xFFFFFFFFu
#define QSCALE 25.0f
#define INVN2S2 (-2.0f / (QSCALE * QSCALE))  /* -2/625 */

typedef float f32x4 __attribute__((ext_vector_type(4)));
typedef int i32x4 __attribute__((ext_vector_type(4)));
typedef unsigned short u16x8 __attribute__((ext_vector_type(8)));

// ---------- packed (quantized-key | index) selection primitives ----------
// key: fp32 -> monotone u32 (total order), top 20 bits kept; low 12 bits = column index.
// min() on packed = (key, then smaller index) — matches stable top_k tie-break.
__device__ __forceinline__ unsigned packkey(float kf, int j) {
    unsigned uk = __float_as_uint(kf);
    uk ^= (unsigned)((int)uk >> 31) | 0x80000000u;
    return (uk & 0xFFFFF000u) | (unsigned)j;
}

__device__ __forceinline__ void uswap(unsigned& a, unsigned& b) {
    unsigned mn = min(a, b), mx = max(a, b);
    a = mn; b = mx;
}

// Merge two sorted-ascending 5-lists (packed), keep 5 smallest — 25 min/max ops.
__device__ __forceinline__ void merge5u(unsigned (&a)[5], const unsigned (&b)[5]) {
    unsigned c0 = min(a[0], b[0]);
    unsigned c1 = min(min(a[1], max(a[0], b[0])), b[1]);
    unsigned c2 = min(min(a[2], max(a[1], b[0])), min(max(a[0], b[1]), b[2]));
    unsigned c3 = min(min(a[3], max(a[2], b[0])),
                      min(max(a[1], b[1]), min(max(a[0], b[2]), b[3])));
    unsigned c4 = min(min(a[4], max(a[3], b[0])),
                      min(max(a[2], b[1]),
                          min(max(a[1], b[2]), min(max(a[0], b[3]), b[4]))));
    a[0] = c0; a[1] = c1; a[2] = c2; a[3] = c3; a[4] = c4;
}

// fp32 -> int8 quantize: clamp(round(x*25), -127, 127)
__device__ __forceinline__ int q8(float x) {
    int v = __float2int_rn(x * QSCALE);
    return min(127, max(-127, v));
}

// ---------- kernel A: global fp32 -> Mq int8 + row sumsq ----------
__global__ __launch_bounds__(256) void split_sumsq_kernel(const float* __restrict__ M,
                                                          unsigned char* __restrict__ Mq,
                                                          float* __restrict__ sq) {
    const int row = blockIdx.x * 4 + (threadIdx.x >> 6);
    const int lane = threadIdx.x & 63;
    const float* p = M + (size_t)row * ND + lane * 8;
    float4 v0 = *(const float4*)p;
    float4 v1 = *(const float4*)(p + 4);
    unsigned lo = (unsigned)(q8(v0.x) & 255) | ((unsigned)(q8(v0.y) & 255) << 8) |
                  ((unsigned)(q8(v0.z) & 255) << 16) | ((unsigned)(q8(v0.w) & 255) << 24);
    unsigned hi = (unsigned)(q8(v1.x) & 255) | ((unsigned)(q8(v1.y) & 255) << 8) |
                  ((unsigned)(q8(v1.z) & 255) << 16) | ((unsigned)(q8(v1.w) & 255) << 24);
    uint2 pk; pk.x = lo; pk.y = hi;
    *(uint2*)&Mq[(size_t)row * ND + lane * 8] = pk;
    float s = v0.x * v0.x + v0.y * v0.y + v0.z * v0.z + v0.w * v0.w
            + v1.x * v1.x + v1.y * v1.y + v1.z * v1.z + v1.w * v1.w;
#pragma unroll
    for (int off = 32; off >= 1; off >>= 1) s += __shfl_down(s, off, 64);
    if (lane == 0) sq[row] = s;
}

// ---------- staging: 6 global_load_lds units per wave, source-swizzled ----------
// Unit u (0..23): u<8 -> A rows u*16.. ; u>=8 -> B rows (u-8)*16..  (64 B / row)
__device__ __forceinline__ void stage_chunk(const unsigned char* __restrict__ Mq,
                                            char* smem, int buf, int kc,
                                            int i0, int jb, int wid, int lane) {
#pragma unroll
    for (int s2 = 0; s2 < 6; ++s2) {
        const int u = wid * 6 + s2;
        const int isB = (u >= 8);
        const int v = isB ? (u - 8) : u;
        const int rl = v * 16 + (lane >> 2);          // tile-local row
        const int gg = (lane & 3) ^ ((rl >> 1) & 3);  // swizzled 16B slot in row
        const int grow = (isB ? jb : i0) + rl;
        const unsigned char* src = Mq + (size_t)grow * ND + kc + gg * 16;
        char* dst = smem + buf * LDSBUF + isB * 8192 + v * 1024;
        __builtin_amdgcn_global_load_lds(
            (const __attribute__((address_space(1))) void*)src,
            (__attribute__((address_space(3))) void*)dst, 16, 0, 0);
    }
}

// ---------- kernel B: MFMA (i8, swapped operands) + fused per-row top-5 ----------
// Triple-buffered LDS, stage depth 2, counted vmcnt(6) (never drain to 0 in loop),
// raw s_barrier; chunk loop fully unrolled. A/B share the slot->k permutation so
// any k-reorder cancels in the dot product. acc is exact int32.
__global__ __launch_bounds__(256, 2) void dist_topk_kernel(const unsigned char* __restrict__ Mq,
                                                           const float* __restrict__ sq,
                                                           unsigned* __restrict__ tvals) {
    extern __shared__ char smem[];
    const int tid = threadIdx.x;
    const int lane = tid & 63;
    const int wid = tid >> 6;       // 0..3
    const int wr = wid >> 1;        // wave-row 0..1 (i rows wr*64)
    const int wc = wid & 1;         // wave-col 0..1 (j cols wc*128)
    const int col16 = lane & 15;
    const int g = lane >> 4;        // k-group 0..3
    const int i0 = blockIdx.x * BM;
    const int jb = blockIdx.y * BN;

    i32x4 acc[4][8];
    const i32x4 zero = {0, 0, 0, 0};
#pragma unroll
    for (int m = 0; m < 4; ++m)
#pragma unroll
        for (int n = 0; n < 8; ++n) acc[m][n] = zero;

    // prologue: 2 chunks in flight (12 loads/wave)
    stage_chunk(Mq, smem, 0, 0, i0, jb, wid, lane);
    stage_chunk(Mq, smem, 1, BKB, i0, jb, wid, lane);

#pragma unroll
    for (int c = 0; c < CHUNKS; ++c) {
        // wait for stage(c): leaves stage(c+1) (6 loads) in flight, except last chunk
        if (c == CHUNKS - 1)
            asm volatile("s_waitcnt vmcnt(0)" ::: "memory");
        else
            asm volatile("s_waitcnt vmcnt(6)" ::: "memory");
        __builtin_amdgcn_s_barrier();
        // safe: buf[(c+2)%3] was last read in compute(c-1); all waves passed the barrier
        if (c + 2 < CHUNKS)
            stage_chunk(Mq, smem, (c + 2) % 3, (c + 2) * BKB, i0, jb, wid, lane);

        const char* bp = smem + (c % 3) * LDSBUF;
        i32x4 aq[4], bq[8];
#pragma unroll
        for (int m = 0; m < 4; ++m) {
            const int r = wr * 64 + m * 16 + col16;
            aq[m] = *(const i32x4*)(bp + r * 64 + ((g ^ ((r >> 1) & 3)) << 4));
        }
#pragma unroll
        for (int n = 0; n < 8; ++n) {
            const int r = wc * 128 + n * 16 + col16;
            bq[n] = *(const i32x4*)(bp + 8192 + r * 64 + ((g ^ ((r >> 1) & 3)) << 4));
        }
        // swapped operands: D[j][i] — i rides the lane (col) axis
#pragma unroll
        for (int m = 0; m < 4; ++m)
#pragma unroll
            for (int n = 0; n < 8; ++n)
                acc[m][n] = __builtin_amdgcn_mfma_i32_16x16x64_i8(bq[n], aq[m], acc[m][n], 0, 0, 0);
    }

    __syncthreads();  // all LDS reads done; alias selection buffer
    unsigned* selp = (unsigned*)smem;  // [128][2][5] packed

    // sq[j] for this lane's 32 j-candidates: j = jb + wc*128 + n*16 + g*4 + r
    float4 sqv[8];
#pragma unroll
    for (int n = 0; n < 8; ++n)
        sqv[n] = *(const float4*)&sq[jb + wc * 128 + n * 16 + g * 4];

    const bool diag = (jb < i0 + BM) && (i0 < jb + BN);  // wave-uniform

#pragma unroll
    for (int m = 0; m < 4; ++m) {
        const int ig = i0 + wr * 64 + m * 16 + col16;  // this lane's global i row
        unsigned run[5] = {UMAXV, UMAXV, UMAXV, UMAXV, UMAXV};
#pragma unroll
        for (int n = 0; n < 8; ++n) {
            const int jg0 = jb + wc * 128 + n * 16 + g * 4;
            // key = sq[j] - 2*dot_q/s^2  (monotone in d^2 per row i, up to quant noise)
            unsigned q0 = packkey(fmaf(INVN2S2, (float)acc[m][n][0], sqv[n].x), jg0 + 0);
            unsigned q1 = packkey(fmaf(INVN2S2, (float)acc[m][n][1], sqv[n].y), jg0 + 1);
            unsigned q2 = packkey(fmaf(INVN2S2, (float)acc[m][n][2], sqv[n].z), jg0 + 2);
            unsigned q3 = packkey(fmaf(INVN2S2, (float)acc[m][n][3], sqv[n].w), jg0 + 3);
            if (diag) {  // mask diagonal (only possible in near-diagonal tiles)
                if (jg0 + 0 == ig) q0 = UMAXV;
                if (jg0 + 1 == ig) q1 = UMAXV;
                if (jg0 + 2 == ig) q2 = UMAXV;
                if (jg0 + 3 == ig) q3 = UMAXV;
            }
            uswap(q0, q1); uswap(q2, q3); uswap(q0, q2); uswap(q1, q3); uswap(q1, q2);
            unsigned curl[5] = {q0, q1, q2, q3, UMAXV};
            merge5u(run, curl);
        }
        // butterfly across the 4 k-group lanes sharing this i (xor 16, 32)
#pragma unroll
        for (int msk = 16; msk <= 32; msk <<= 1) {
            unsigned xv[5];
#pragma unroll
            for (int s = 0; s < 5; ++s) xv[s] = __shfl_xor(run[s], msk, 64);
            merge5u(run, xv);
        }
        if (g == 0) {
            const int rloc = wr * 64 + m * 16 + col16;
#pragma unroll
            for (int s = 0; s < 5; ++s) selp[(rloc * 2 + wc) * 5 + s] = run[s];
        }
    }
    __syncthreads();
    if (tid < BM) {
        unsigned a[5], b[5];
#pragma unroll
        for (int s = 0; s < 5; ++s) {
            a[s] = selp[(tid * 2 + 0) * 5 + s];
            b[s] = selp[(tid * 2 + 1) * 5 + s];
        }
        merge5u(a, b);
        const size_t base = ((size_t)(i0 + tid) * NSPLIT + blockIdx.y) * KNB;
#pragma unroll
        for (int s = 0; s < 5; ++s) tvals[base + s] = a[s];
    }
}

// ---------- kernel C: two rows per wave — packed 16-list merge (lanes 0-15 row0,
//            lanes 16-31 row1) + dual gather for 2x memory-level parallelism ----------
__global__ __launch_bounds__(256) void loss_kernel(const float* __restrict__ M,
                                                   const float* __restrict__ V1,
                                                   const unsigned* __restrict__ tvals,
                                                   float* __restrict__ partial) {
    const int wid = threadIdx.x >> 6;
    const int lane = threadIdx.x & 63;
    const int row0 = blockIdx.x * 8 + wid * 2;  // this wave's two rows
    const int row1 = row0 + 1;

    // lanes 0-15: row0's 16 lists; lanes 16-31: row1's 16 lists; 32-63: +INF
    unsigned a[5];
    if (lane < 32) {
        const int r = (lane < NSPLIT) ? row0 : row1;
        const int sl = lane & 15;
        const size_t base = (size_t)r * (NSPLIT * KNB) + sl * KNB;
#pragma unroll
        for (int s = 0; s < 5; ++s) a[s] = tvals[base + s];
    } else {
#pragma unroll
        for (int s = 0; s < 5; ++s) a[s] = UMAXV;
    }
    // butterfly within each 16-lane group (xor 1,2,4,8 never crosses groups)
#pragma unroll
    for (int msk = 1; msk <= 8; msk <<= 1) {
        unsigned bv[5];
#pragma unroll
        for (int s = 0; s < 5; ++s) bv[s] = __shfl_xor(a[s], msk, 64);
        merge5u(a, bv);
    }
    int nb0[5], nb1[5];
#pragma unroll
    for (int s = 0; s < 5; ++s) {
        nb0[s] = __shfl((int)(a[s] & 0xFFFu), 0, 64);   // row0 top-5 (from lane 0)
        nb1[s] = __shfl((int)(a[s] & 0xFFFu), 16, 64);  // row1 top-5 (from lane 16)
    }

    const int d0 = lane * 8;  // each lane covers 8 dims of BOTH rows (24 loads in flight)
    float xa[5][8], xb[5][8], pva[8], pvb[8];
#pragma unroll
    for (int s = 0; s < 5; ++s) {
        *(float4*)&xa[s][0] = *(const float4*)&M[(size_t)nb0[s] * ND + d0];
        *(float4*)&xa[s][4] = *(const float4*)&M[(size_t)nb0[s] * ND + d0 + 4];
        *(float4*)&xb[s][0] = *(const float4*)&M[(size_t)nb1[s] * ND + d0];
        *(float4*)&xb[s][4] = *(const float4*)&M[(size_t)nb1[s] * ND + d0 + 4];
    }
    *(float4*)&pva[0] = *(const float4*)&V1[(size_t)row0 * ND + d0];
    *(float4*)&pva[4] = *(const float4*)&V1[(size_t)row0 * ND + d0 + 4];
    *(float4*)&pvb[0] = *(const float4*)&V1[(size_t)row1 * ND + d0];
    *(float4*)&pvb[4] = *(const float4*)&V1[(size_t)row1 * ND + d0 + 4];

    float lsum0 = 0.f, lsum1 = 0.f;
#pragma unroll
    for (int e = 0; e < 8; ++e) {
        {
            float mean = (xa[0][e] + xa[1][e] + xa[2][e] + xa[3][e] + xa[4][e]) * 0.2f;
            float e0 = xa[0][e] - mean, e1 = xa[1][e] - mean, e2 = xa[2][e] - mean,
                  e3 = xa[3][e] - mean, e4 = xa[4][e] - mean;
            float var = (e0 * e0 + e1 * e1 + e2 * e2 + e3 * e3 + e4 * e4) * 0.25f;  // ddof=1
            float df = expf(0.5f * pva[e]) - sqrtf(var);
            lsum0 = fmaf(df, df, lsum0);
        }
        {
            float mean = (xb[0][e] + xb[1][e] + xb[2][e] + xb[3][e] + xb[4][e]) * 0.2f;
            float e0 = xb[0][e] - mean, e1 = xb[1][e] - mean, e2 = xb[2][e] - mean,
                  e3 = xb[3][e] - mean, e4 = xb[4][e] - mean;
            float var = (e0 * e0 + e1 * e1 + e2 * e2 + e3 * e3 + e4 * e4) * 0.25f;
            float df = expf(0.5f * pvb[e]) - sqrtf(var);
            lsum1 = fmaf(df, df, lsum1);
        }
    }
#pragma unroll
    for (int off = 32; off >= 1; off >>= 1) {
        lsum0 += __shfl_down(lsum0, off, 64);
        lsum1 += __shfl_down(lsum1, off, 64);
    }
    if (lane == 0) {
        partial[row0] = lsum0;
        partial[row1] = lsum1;
    }
}

// ---------- kernel D: deterministic final reduction ----------
__global__ __launch_bounds__(256) void finalize_kernel(const float* __restrict__ partial,
                                                       float* __restrict__ out) {
    const int tid = threadIdx.x;
    double s = 0.0;
    for (int i = tid; i < NB; i += 256) s += (double)partial[i];
#pragma unroll
    for (int off = 32; off >= 1; off >>= 1) s += __shfl_down(s, off, 64);
    __shared__ double dsum[4];
    if ((tid & 63) == 0) dsum[tid >> 6] = s;
    __syncthreads();
    if (tid == 0)
        out[0] = (float)(((dsum[0] + dsum[1]) + (dsum[2] + dsum[3])) / ((double)NB * (double)ND));
}

extern "C" void kernel_launch(void* const* d_in, const int* in_sizes, int n_in,
                              void* d_out, int out_size, void* d_ws, size_t ws_size,
                              hipStream_t stream) {
    const float* mean1 = (const float*)d_in[0];
    const float* var1 = (const float*)d_in[1];

    char* ws = (char*)d_ws;
    unsigned char* Mq = (unsigned char*)ws;                        // 2 MB
    float* sq = (float*)(ws + (size_t)NB * ND);                    // 16 KB
    unsigned* tvals = (unsigned*)(ws + (size_t)NB * ND + NB * 4);  // 1.31 MB packed
    float* partial = (float*)(ws + (size_t)NB * ND + NB * 4 + (size_t)NB * NSPLIT * KNB * 4);
    float* out = (float*)d_out;

    (void)hipFuncSetAttribute((const void*)dist_topk_kernel,
                              hipFuncAttributeMaxDynamicSharedMemorySize, 3 * LDSBUF);

    split_sumsq_kernel<<<NB / 4, 256, 0, stream>>>(mean1, Mq, sq);
    dist_topk_kernel<<<dim3(NB / BM, NB / BN), 256, 3 * LDSBUF, stream>>>(Mq, sq, tvals);
    loss_kernel<<<NB / 8, 256, 0, stream>>>(mean1, var1, tvals, partial);
    finalize_kernel<<<1, 256, 0, stream>>>(partial, out);
}

// Round 14
// 38.097 us; speedup vs baseline: 1.0179x; 1.0179x over previous
//
#include <hip/hip_runtime.h>
#include <math.h>

#define NB 4096
#define ND 512
#define BM 128
#define BN 256
#define NLIST 32    /* lists per row = 2 * NB/BN (one per wc-half per j-strip) */
#define KNB 5
#define BKB 64           /* bytes (i8 elems) per row per chunk */
#define CHUNKS (ND / BKB) /* 8 */
#define LDSBUF 24576     /* A:128x64B (8KB) + B:256x64B (16KB) i8 */
#define UMAXV 0xFFFFFFFFu
#define QSCALE 25.0f
#define INVN2S2 (-2.0f / (QSCALE * QSCALE))  /* -2/625 */

typedef float f32x4 __attribute__((ext_vector_type(4)));
typedef int i32x4 __attribute__((ext_vector_type(4)));

// ---------- packed (quantized-key | index) selection primitives ----------
// key: fp32 -> monotone u32 (total order), top 20 bits kept; low 12 bits = column index.
// min() on packed = (key, then smaller index) — matches stable top_k tie-break.
__device__ __forceinline__ unsigned packkey(float kf, int j) {
    unsigned uk = __float_as_uint(kf);
    uk ^= (unsigned)((int)uk >> 31) | 0x80000000u;
    return (uk & 0xFFFFF000u) | (unsigned)j;
}

__device__ __forceinline__ void uswap(unsigned& a, unsigned& b) {
    unsigned mn = min(a, b), mx = max(a, b);
    a = mn; b = mx;
}

// Merge two sorted-ascending 5-lists (packed), keep 5 smallest — 25 min/max ops.
__device__ __forceinline__ void merge5u(unsigned (&a)[5], const unsigned (&b)[5]) {
    unsigned c0 = min(a[0], b[0]);
    unsigned c1 = min(min(a[1], max(a[0], b[0])), b[1]);
    unsigned c2 = min(min(a[2], max(a[1], b[0])), min(max(a[0], b[1]), b[2]));
    unsigned c3 = min(min(a[3], max(a[2], b[0])),
                      min(max(a[1], b[1]), min(max(a[0], b[2]), b[3])));
    unsigned c4 = min(min(a[4], max(a[3], b[0])),
                      min(max(a[2], b[1]),
                          min(max(a[1], b[2]), min(max(a[0], b[3]), b[4]))));
    a[0] = c0; a[1] = c1; a[2] = c2; a[3] = c3; a[4] = c4;
}

// fp32 -> int8 quantize: clamp(round(x*25), -127, 127)
__device__ __forceinline__ int q8(float x) {
    int v = __float2int_rn(x * QSCALE);
    return min(127, max(-127, v));
}

// ---------- kernel A: global fp32 -> Mq int8 + row sumsq ----------
__global__ __launch_bounds__(256) void split_sumsq_kernel(const float* __restrict__ M,
                                                          unsigned char* __restrict__ Mq,
                                                          float* __restrict__ sq) {
    const int row = blockIdx.x * 4 + (threadIdx.x >> 6);
    const int lane = threadIdx.x & 63;
    const float* p = M + (size_t)row * ND + lane * 8;
    float4 v0 = *(const float4*)p;
    float4 v1 = *(const float4*)(p + 4);
    unsigned lo = (unsigned)(q8(v0.x) & 255) | ((unsigned)(q8(v0.y) & 255) << 8) |
                  ((unsigned)(q8(v0.z) & 255) << 16) | ((unsigned)(q8(v0.w) & 255) << 24);
    unsigned hi = (unsigned)(q8(v1.x) & 255) | ((unsigned)(q8(v1.y) & 255) << 8) |
                  ((unsigned)(q8(v1.z) & 255) << 16) | ((unsigned)(q8(v1.w) & 255) << 24);
    uint2 pk; pk.x = lo; pk.y = hi;
    *(uint2*)&Mq[(size_t)row * ND + lane * 8] = pk;
    float s = v0.x * v0.x + v0.y * v0.y + v0.z * v0.z + v0.w * v0.w
            + v1.x * v1.x + v1.y * v1.y + v1.z * v1.z + v1.w * v1.w;
#pragma unroll
    for (int off = 32; off >= 1; off >>= 1) s += __shfl_down(s, off, 64);
    if (lane == 0) sq[row] = s;
}

// ---------- staging: 6 global_load_lds units per wave, source-swizzled ----------
// Unit u (0..23): u<8 -> A rows u*16.. ; u>=8 -> B rows (u-8)*16..  (64 B / row)
__device__ __forceinline__ void stage_chunk(const unsigned char* __restrict__ Mq,
                                            char* smem, int buf, int kc,
                                            int i0, int jb, int wid, int lane) {
#pragma unroll
    for (int s2 = 0; s2 < 6; ++s2) {
        const int u = wid * 6 + s2;
        const int isB = (u >= 8);
        const int v = isB ? (u - 8) : u;
        const int rl = v * 16 + (lane >> 2);          // tile-local row
        const int gg = (lane & 3) ^ ((rl >> 1) & 3);  // swizzled 16B slot in row
        const int grow = (isB ? jb : i0) + rl;
        const unsigned char* src = Mq + (size_t)grow * ND + kc + gg * 16;
        char* dst = smem + buf * LDSBUF + isB * 8192 + v * 1024;
        __builtin_amdgcn_global_load_lds(
            (const __attribute__((address_space(1))) void*)src,
            (__attribute__((address_space(3))) void*)dst, 16, 0, 0);
    }
}

// ---------- kernel B: MFMA (i8, swapped operands) + fused per-row top-5 ----------
// Triple-buffered LDS, stage depth 2, counted vmcnt(6) (never drain to 0 in loop),
// raw s_barrier; chunk loop fully unrolled. A/B share the slot->k permutation so
// any k-reorder cancels in the dot product. acc is exact int32. Each wc-half
// writes its own top-5 list directly (no cross-wave merge; loss merges 32 lists).
__global__ __launch_bounds__(256, 2) void dist_topk_kernel(const unsigned char* __restrict__ Mq,
                                                           const float* __restrict__ sq,
                                                           unsigned* __restrict__ tvals) {
    extern __shared__ char smem[];
    const int tid = threadIdx.x;
    const int lane = tid & 63;
    const int wid = tid >> 6;       // 0..3
    const int wr = wid >> 1;        // wave-row 0..1 (i rows wr*64)
    const int wc = wid & 1;         // wave-col 0..1 (j cols wc*128)
    const int col16 = lane & 15;
    const int g = lane >> 4;        // k-group 0..3
    const int i0 = blockIdx.x * BM;
    const int jb = blockIdx.y * BN;

    i32x4 acc[4][8];
    const i32x4 zero = {0, 0, 0, 0};
#pragma unroll
    for (int m = 0; m < 4; ++m)
#pragma unroll
        for (int n = 0; n < 8; ++n) acc[m][n] = zero;

    // prologue: 2 chunks in flight (12 loads/wave)
    stage_chunk(Mq, smem, 0, 0, i0, jb, wid, lane);
    stage_chunk(Mq, smem, 1, BKB, i0, jb, wid, lane);

#pragma unroll
    for (int c = 0; c < CHUNKS; ++c) {
        // wait for stage(c): leaves stage(c+1) (6 loads) in flight, except last chunk
        if (c == CHUNKS - 1)
            asm volatile("s_waitcnt vmcnt(0)" ::: "memory");
        else
            asm volatile("s_waitcnt vmcnt(6)" ::: "memory");
        __builtin_amdgcn_s_barrier();
        // safe: buf[(c+2)%3] was last read in compute(c-1); all waves passed the barrier
        if (c + 2 < CHUNKS)
            stage_chunk(Mq, smem, (c + 2) % 3, (c + 2) * BKB, i0, jb, wid, lane);

        const char* bp = smem + (c % 3) * LDSBUF;
        i32x4 aq[4], bq[8];
#pragma unroll
        for (int m = 0; m < 4; ++m) {
            const int r = wr * 64 + m * 16 + col16;
            aq[m] = *(const i32x4*)(bp + r * 64 + ((g ^ ((r >> 1) & 3)) << 4));
        }
#pragma unroll
        for (int n = 0; n < 8; ++n) {
            const int r = wc * 128 + n * 16 + col16;
            bq[n] = *(const i32x4*)(bp + 8192 + r * 64 + ((g ^ ((r >> 1) & 3)) << 4));
        }
        // swapped operands: D[j][i] — i rides the lane (col) axis
#pragma unroll
        for (int m = 0; m < 4; ++m)
#pragma unroll
            for (int n = 0; n < 8; ++n)
                acc[m][n] = __builtin_amdgcn_mfma_i32_16x16x64_i8(bq[n], aq[m], acc[m][n], 0, 0, 0);
    }

    // no further LDS use — selection is fully in-register + shfl
    // sq[j] for this lane's 32 j-candidates: j = jb + wc*128 + n*16 + g*4 + r
    float4 sqv[8];
#pragma unroll
    for (int n = 0; n < 8; ++n)
        sqv[n] = *(const float4*)&sq[jb + wc * 128 + n * 16 + g * 4];

    const bool diag = (jb < i0 + BM) && (i0 < jb + BN);  // wave-uniform

#pragma unroll
    for (int m = 0; m < 4; ++m) {
        const int ig = i0 + wr * 64 + m * 16 + col16;  // this lane's global i row
        unsigned run[5] = {UMAXV, UMAXV, UMAXV, UMAXV, UMAXV};
#pragma unroll
        for (int n = 0; n < 8; ++n) {
            const int jg0 = jb + wc * 128 + n * 16 + g * 4;
            // key = sq[j] - 2*dot_q/s^2  (monotone in d^2 per row i, up to quant noise)
            unsigned q0 = packkey(fmaf(INVN2S2, (float)acc[m][n][0], sqv[n].x), jg0 + 0);
            unsigned q1 = packkey(fmaf(INVN2S2, (float)acc[m][n][1], sqv[n].y), jg0 + 1);
            unsigned q2 = packkey(fmaf(INVN2S2, (float)acc[m][n][2], sqv[n].z), jg0 + 2);
            unsigned q3 = packkey(fmaf(INVN2S2, (float)acc[m][n][3], sqv[n].w), jg0 + 3);
            if (diag) {  // mask diagonal (only possible in near-diagonal tiles)
                if (jg0 + 0 == ig) q0 = UMAXV;
                if (jg0 + 1 == ig) q1 = UMAXV;
                if (jg0 + 2 == ig) q2 = UMAXV;
                if (jg0 + 3 == ig) q3 = UMAXV;
            }
            uswap(q0, q1); uswap(q2, q3); uswap(q0, q2); uswap(q1, q3); uswap(q1, q2);
            unsigned curl[5] = {q0, q1, q2, q3, UMAXV};
            merge5u(run, curl);
        }
        // butterfly across the 4 k-group lanes sharing this i (xor 16, 32)
#pragma unroll
        for (int msk = 16; msk <= 32; msk <<= 1) {
            unsigned xv[5];
#pragma unroll
            for (int s = 0; s < 5; ++s) xv[s] = __shfl_xor(run[s], msk, 64);
            merge5u(run, xv);
        }
        if (g == 0) {
            // write this wc-half's list directly: list index = blockIdx.y*2 + wc
            const int row = i0 + wr * 64 + m * 16 + col16;
            const size_t base = ((size_t)row * NLIST + blockIdx.y * 2 + wc) * KNB;
#pragma unroll
            for (int s = 0; s < 5; ++s) tvals[base + s] = run[s];
        }
    }
}

// ---------- kernel C: one wave per row — packed 32-list merge + std(ddof=1) + MSE ----------
__global__ __launch_bounds__(256) void loss_kernel(const float* __restrict__ M,
                                                   const float* __restrict__ V1,
                                                   const unsigned* __restrict__ tvals,
                                                   float* __restrict__ partial) {
    const int row = blockIdx.x * 4 + (threadIdx.x >> 6);
    const int lane = threadIdx.x & 63;

    unsigned a[5];
    if (lane < NLIST) {
        const size_t base = (size_t)row * (NLIST * KNB) + lane * KNB;
#pragma unroll
        for (int s = 0; s < 5; ++s) a[s] = tvals[base + s];
    } else {
#pragma unroll
        for (int s = 0; s < 5; ++s) a[s] = UMAXV;
    }
#pragma unroll
    for (int msk = 1; msk <= 16; msk <<= 1) {
        unsigned bv[5];
#pragma unroll
        for (int s = 0; s < 5; ++s) bv[s] = __shfl_xor(a[s], msk, 64);
        merge5u(a, bv);
    }
    const int n0 = __shfl((int)(a[0] & 0xFFFu), 0, 64);
    const int n1 = __shfl((int)(a[1] & 0xFFFu), 0, 64);
    const int n2 = __shfl((int)(a[2] & 0xFFFu), 0, 64);
    const int n3 = __shfl((int)(a[3] & 0xFFFu), 0, 64);
    const int n4 = __shfl((int)(a[4] & 0xFFFu), 0, 64);

    const int d0 = lane * 8;
    float x0[8], x1[8], x2[8], x3[8], x4[8], pv[8];
    *(float4*)&x0[0] = *(const float4*)&M[(size_t)n0 * ND + d0];
    *(float4*)&x0[4] = *(const float4*)&M[(size_t)n0 * ND + d0 + 4];
    *(float4*)&x1[0] = *(const float4*)&M[(size_t)n1 * ND + d0];
    *(float4*)&x1[4] = *(const float4*)&M[(size_t)n1 * ND + d0 + 4];
    *(float4*)&x2[0] = *(const float4*)&M[(size_t)n2 * ND + d0];
    *(float4*)&x2[4] = *(const float4*)&M[(size_t)n2 * ND + d0 + 4];
    *(float4*)&x3[0] = *(const float4*)&M[(size_t)n3 * ND + d0];
    *(float4*)&x3[4] = *(const float4*)&M[(size_t)n3 * ND + d0 + 4];
    *(float4*)&x4[0] = *(const float4*)&M[(size_t)n4 * ND + d0];
    *(float4*)&x4[4] = *(const float4*)&M[(size_t)n4 * ND + d0 + 4];
    *(float4*)&pv[0] = *(const float4*)&V1[(size_t)row * ND + d0];
    *(float4*)&pv[4] = *(const float4*)&V1[(size_t)row * ND + d0 + 4];

    float lsum = 0.f;
#pragma unroll
    for (int e = 0; e < 8; ++e) {
        float mean = (x0[e] + x1[e] + x2[e] + x3[e] + x4[e]) * 0.2f;
        float e0 = x0[e] - mean, e1 = x1[e] - mean, e2 = x2[e] - mean,
              e3 = x3[e] - mean, e4 = x4[e] - mean;
        float var = (e0 * e0 + e1 * e1 + e2 * e2 + e3 * e3 + e4 * e4) * 0.25f;  // ddof=1
        float nstd = sqrtf(var);
        float pred = expf(0.5f * pv[e]);  // sqrt(exp(v))
        float df = pred - nstd;
        lsum = fmaf(df, df, lsum);
    }
#pragma unroll
    for (int off = 32; off >= 1; off >>= 1) lsum += __shfl_down(lsum, off, 64);
    if (lane == 0) partial[row] = lsum;
}

// ---------- kernel D: deterministic final reduction ----------
__global__ __launch_bounds__(256) void finalize_kernel(const float* __restrict__ partial,
                                                       float* __restrict__ out) {
    const int tid = threadIdx.x;
    double s = 0.0;
    for (int i = tid; i < NB; i += 256) s += (double)partial[i];
#pragma unroll
    for (int off = 32; off >= 1; off >>= 1) s += __shfl_down(s, off, 64);
    __shared__ double dsum[4];
    if ((tid & 63) == 0) dsum[tid >> 6] = s;
    __syncthreads();
    if (tid == 0)
        out[0] = (float)(((dsum[0] + dsum[1]) + (dsum[2] + dsum[3])) / ((double)NB * (double)ND));
}

extern "C" void kernel_launch(void* const* d_in, const int* in_sizes, int n_in,
                              void* d_out, int out_size, void* d_ws, size_t ws_size,
                              hipStream_t stream) {
    const float* mean1 = (const float*)d_in[0];
    const float* var1 = (const float*)d_in[1];

    char* ws = (char*)d_ws;
    unsigned char* Mq = (unsigned char*)ws;                        // 2 MB
    float* sq = (float*)(ws + (size_t)NB * ND);                    // 16 KB
    unsigned* tvals = (unsigned*)(ws + (size_t)NB * ND + NB * 4);  // 2.62 MB packed
    float* partial = (float*)(ws + (size_t)NB * ND + NB * 4 + (size_t)NB * NLIST * KNB * 4);
    float* out = (float*)d_out;

    (void)hipFuncSetAttribute((const void*)dist_topk_kernel,
                              hipFuncAttributeMaxDynamicSharedMemorySize, 3 * LDSBUF);

    split_sumsq_kernel<<<NB / 4, 256, 0, stream>>>(mean1, Mq, sq);
    dist_topk_kernel<<<dim3(NB / BM, NB / BN), 256, 3 * LDSBUF, stream>>>(Mq, sq, tvals);
    loss_kernel<<<NB / 4, 256, 0, stream>>>(mean1, var1, tvals, partial);
    finalize_kernel<<<1, 256, 0, stream>>>(partial, out);
}